// Round 13
// baseline (174.345 us; speedup 1.0000x reference)
//
#include <hip/hip_runtime.h>
#include <math.h>

static constexpr int IMGS = 2;
static constexpr int H = 128, W = 128;
static constexpr int NP = H * W;           // 16384
static constexpr int KWIN = 30;            // quickshift window radius (ceil(3*10))
static constexpr int PR = 20;              // parent prune radius: dr^2+dc^2>400 can't win (MAX_DIST=20)
static constexpr int GR = 20;              // gaussian radius int(4*5+0.5)
static constexpr float INV = 0.005f;       // 0.5 / (10*10)
static constexpr int MAXSEG = 40;

// padded feature layout: row stride 192 float4, cols [30,158) hold the image.
// float4 = (L, a, b, dens); pads = (1e6,1e6,1e6,-inf).
static constexpr int PSTR = 192;
static constexpr int PIMG = H * PSTR;      // 24576 float4 per image
static constexpr int NSEG = 64 + 2 * PR;   // 104 staged float4 per k_par row

typedef float f32x2 __attribute__((ext_vector_type(2)));

// ---------------- prep: pf sentinel fill + rgb2lab into bufL -------------------
__global__ void k_prep(const float* __restrict__ x, float4* __restrict__ pf,
                       float4* __restrict__ bufL) {
#pragma clang fp contract(off)
  int i = blockIdx.x * blockDim.x + threadIdx.x;
  if (i < IMGS * PIMG) pf[i] = make_float4(1e6f, 1e6f, 1e6f, -__builtin_inff());
  if (i >= IMGS * NP) return;
  int img = i / NP, p = i % NP;
  const float* base = x + img * 3 * NP;
  float rgb[3] = { base[p], base[NP + p], base[2 * NP + p] };
  float lin[3];
  for (int c = 0; c < 3; ++c) {
    float v = rgb[c];
    lin[c] = (v > 0.04045f) ? powf((v + 0.055f) / 1.055f, 2.4f) : (v / 12.92f);
  }
  const float M[3][3] = {{0.412453f, 0.357580f, 0.180423f},
                         {0.212671f, 0.715160f, 0.072169f},
                         {0.019334f, 0.119193f, 0.950227f}};
  const float wp[3] = {0.95047f, 1.0f, 1.08883f};
  float f[3];
  for (int j = 0; j < 3; ++j) {
    float s = lin[0] * M[j][0];
    s = s + lin[1] * M[j][1];
    s = s + lin[2] * M[j][2];
    float xyz = s / wp[j];
    f[j] = (xyz > 0.008856f) ? cbrtf(fmaxf(xyz, 1e-8f))
                             : (7.787f * xyz + (float)(16.0 / 116.0));
  }
  float L = 116.0f * f[1] - 16.0f;
  float a = 500.0f * (f[0] - f[1]);
  float b = 200.0f * (f[1] - f[2]);
  bufL[i] = make_float4(L, a, b, 0.0f);
}

// ---------------- fused separable gaussian (V then H), symmetric pad -----------
__global__ __launch_bounds__(384)
void k_blur(const float4* __restrict__ bufL, float4* __restrict__ pf) {
#pragma clang fp contract(off)
  __shared__ float w[2 * GR + 1];
  __shared__ float mid[3][128];
  if (threadIdx.x == 0) {
    double k[2 * GR + 1];
    double s = 0.0;
    for (int i = -GR; i <= GR; ++i) {
      double t = (double)i / 5.0;
      double v = exp(-0.5 * t * t);
      k[i + GR] = v;
      s += v;
    }
    for (int i = 0; i < 2 * GR + 1; ++i) w[i] = (float)(k[i] / s);
  }
  __syncthreads();
  int tid = threadIdx.x;
  int c = tid >> 7;                         // 0..2
  int xx = tid & 127;
  int b = blockIdx.x;                       // img*128 + y
  int y = b & 127, img = b >> 7;
  const float* base = (const float*)(bufL + img * NP);
  float a = 0.0f;
  for (int t = 0; t <= 2 * GR; ++t) {
    int yy = y - GR + t;
    if (yy < 0) yy = -yy - 1;
    if (yy >= H) yy = 2 * H - 1 - yy;
    a = a + w[t] * base[(yy * W + xx) * 4 + c];
  }
  mid[c][xx] = a;
  __syncthreads();
  float o = 0.0f;
  for (int t = 0; t <= 2 * GR; ++t) {
    int xq = xx - GR + t;
    if (xq < 0) xq = -xq - 1;
    if (xq >= W) xq = 2 * W - 1 - xq;
    o = o + w[t] * mid[c][xq];
  }
  ((float*)(pf + img * PIMG + y * PSTR + xx + KWIN))[c] = o;  // 4B store, no race
}

// ---------------- density: 2-center rows x 4-way row-split, barrier-free -------
// REVERTED to R11's validated version (50.4us). R12's 4-center hit the VGPR
// cap (128) and spilled (WRITE_SIZE 512KB->5.1MB, 58.7us) — third confirmation
// that center-batching beyond 2 exceeds the <=64-VGPR sweet spot on this
// allocator. Density keeps the FULL 61x61 window (no distance cutoff; far
// terms contribute exp(-2)~0.13).
__device__ inline void dens_row2(const float4* __restrict__ grow,
                                 float4 fc0, float4 fc1,
                                 float sprf0, float sprf1, int lane,
                                 float& acc0, float& acc1) {
#pragma clang fp contract(off)
  const f32x2 nInv = { -INV, -INV };
#pragma unroll
  for (int d0 = 0; d0 + 1 < 61; d0 += 2) {
    float4 nb0 = grow[lane + d0];
    float4 nb1 = grow[lane + d0 + 1];
    float c0 = (float)((d0 - KWIN) * (d0 - KWIN));
    float c1 = (float)((d0 + 1 - KWIN) * (d0 + 1 - KWIN));
    // center 0
    f32x2 dx0 = { fc0.x - nb0.x, fc0.x - nb1.x };
    f32x2 dy0 = { fc0.y - nb0.y, fc0.y - nb1.y };
    f32x2 dz0 = { fc0.z - nb0.z, fc0.z - nb1.z };
    f32x2 dd0 = (dx0 * dx0 + dy0 * dy0) + dz0 * dz0;
    f32x2 sp0 = { sprf0 + c0, sprf0 + c1 };   // exact: ints < 2^11 (or inf)
    dd0 = dd0 + sp0;
    f32x2 e0 = dd0 * nInv;                    // bit == -(d*INV)
    acc0 = acc0 + __expf(e0.x);               // in-order within row
    acc0 = acc0 + __expf(e0.y);
    // center 1 (same loaded neighbors)
    f32x2 dx1 = { fc1.x - nb0.x, fc1.x - nb1.x };
    f32x2 dy1 = { fc1.y - nb0.y, fc1.y - nb1.y };
    f32x2 dz1 = { fc1.z - nb0.z, fc1.z - nb1.z };
    f32x2 dd1 = (dx1 * dx1 + dy1 * dy1) + dz1 * dz1;
    f32x2 sp1 = { sprf1 + c0, sprf1 + c1 };
    dd1 = dd1 + sp1;
    f32x2 e1 = dd1 * nInv;
    acc1 = acc1 + __expf(e1.x);
    acc1 = acc1 + __expf(e1.y);
  }
  {                                           // dc = 60 tail, both centers
    float4 nb = grow[lane + 60];
    float ct = (float)((60 - KWIN) * (60 - KWIN));
    float a0 = fc0.x - nb.x, a1 = fc0.y - nb.y, a2 = fc0.z - nb.z;
    float d0 = (a0 * a0 + a1 * a1) + a2 * a2;
    d0 = d0 + (sprf0 + ct);
    acc0 = acc0 + __expf(-d0 * INV);
    float b0 = fc1.x - nb.x, b1 = fc1.y - nb.y, b2 = fc1.z - nb.z;
    float d1 = (b0 * b0 + b1 * b1) + b2 * b2;
    d1 = d1 + (sprf1 + ct);
    acc1 = acc1 + __expf(-d1 * INV);
  }
}

__global__ __launch_bounds__(512, 4)
void k_dens(const float4* __restrict__ pf, float* __restrict__ part) {
#pragma clang fp contract(off)
  __shared__ float pbuf[8][2][64];
  int tid = threadIdx.x;
  int lane = tid & 63;
  int wave = tid >> 6;
  int b = blockIdx.x;                      // 1024: img*512 + ygrp*8 + tile*4 + q
  int q = b & 3, tile = (b >> 2) & 1, ygrp = (b >> 3) & 63, img = b >> 9;
  int y0 = ygrp * 2, y1 = y0 + 1;
  int x0 = tile * 64;
  const float4* fimg = pf + img * PIMG;
  float4 fc0 = fimg[y0 * PSTR + x0 + lane + KWIN];
  float4 fc1 = fimg[y1 * PSTR + x0 + lane + KWIN];
  int lo = y0 - KWIN; if (lo < 0) lo = 0;
  int hi = y1 + KWIN; if (hi > H - 1) hi = H - 1;
  int nr = hi - lo + 1;                    // 32..62 union rows
  int c = q * 8 + wave;                    // 0..31 ascending row chunks
  int base = nr >> 5, rem = nr & 31;       // base>=1, so all chunks nonempty
  int cnt = base + (c < rem ? 1 : 0);
  int start = lo + c * base + (c < rem ? c : rem);
  float acc0 = 0.0f, acc1 = 0.0f;
  for (int r = 0; r < cnt; ++r) {
    int ny = start + r;
    int dr0 = ny - y0, dr1 = ny - y1;
    // wave-uniform activity guards; inactive => sprf=inf => exact +0.0 terms
    float s0 = (ny <= y0 + KWIN) ? (float)(dr0 * dr0) : __builtin_inff();
    float s1 = (ny >= y1 - KWIN) ? (float)(dr1 * dr1) : __builtin_inff();
    const float4* grow = fimg + ny * PSTR + x0;
    dens_row2(grow, fc0, fc1, s0, s1, lane, acc0, acc1);
  }
  pbuf[wave][0][lane] = acc0;              // publish row-chunk partials
  pbuf[wave][1][lane] = acc1;
  __syncthreads();
  if (wave < 2) {                          // wave w folds center row y0+w
    float a = pbuf[0][wave][lane];
#pragma unroll
    for (int w = 1; w < 8; ++w) a = a + pbuf[w][wave][lane];
    part[q * (IMGS * NP) + img * NP + (y0 + wave) * W + x0 + lane] = a;
  }
}

// ---------------- fold the 4 row-quarter partials into pf.w + root init --------
// Ascending-q = ascending-row order, left-to-right: bitwise-deterministic.
// R28: also initializes root=-1 here (was in k_merge, now removed); runs
// before k_par/k_root in-stream, so ordering is safe.
__global__ void k_densmerge(const float* __restrict__ part, float4* __restrict__ pf,
                            int* __restrict__ root) {
#pragma clang fp contract(off)
  int i = blockIdx.x * blockDim.x + threadIdx.x;
  if (i >= IMGS * NP) return;
  int img = i / NP, p = i % NP, y = p >> 7, x = p & 127;
  float s = ((part[i] + part[IMGS * NP + i]) + part[2 * IMGS * NP + i])
            + part[3 * IMGS * NP + i];
  pf[img * PIMG + y * PSTR + x + KWIN].w = s;
  root[i] = -1;                            // enables the k_root shortcut
}

// ---------------- parent: +-20 pruned window, half-split, AoS b128, pairs ------
// (R11, validated: semantic prune — MAX_DIST=20 means dr^2+dc^2>400 candidates
// can never be sub-threshold winners; 41x41 window = 45% of the work.)
template<int DB, int DE>
__device__ inline void par_pairs(const float4* __restrict__ rb,
                                 int lane, f32x2 fcx, f32x2 fcy, f32x2 fcz,
                                 float dcen, float sprf, int qbase,
                                 float& bestd, int& bestp) {
#pragma clang fp contract(off)
#pragma unroll
  for (int d0 = DB; d0 + 1 < DE; d0 += 2) {
    int i0 = lane + d0;
    float4 nb0 = rb[i0];
    float4 nb1 = rb[i0 + 1];
    f32x2 nx = { nb0.x, nb1.x };
    f32x2 nv = { nb0.y, nb1.y };
    f32x2 nz = { nb0.z, nb1.z };
    f32x2 nw = { nb0.w, nb1.w };
    f32x2 dx = fcx - nx, dy = fcy - nv, dz = fcz - nz;
    f32x2 dd = (dx * dx + dy * dy) + dz * dz;
    f32x2 sp = { sprf + (float)((d0 - PR) * (d0 - PR)),
                 sprf + (float)((d0 + 1 - PR) * (d0 + 1 - PR)) };
    dd = dd + sp;                          // exact (ints < 2^11)
    int b0 = (nw.x > dcen) & (dd.x < bestd);
    bestd = b0 ? dd.x : bestd;
    bestp = b0 ? (qbase + d0 - PR) : bestp;
    int b1 = (nw.y > dcen) & (dd.y < bestd);
    bestd = b1 ? dd.y : bestd;
    bestp = b1 ? (qbase + d0 + 1 - PR) : bestp;
  }
  if constexpr ((DE - DB) & 1) {           // scalar tail
    constexpr int dcu = DE - 1;
    float4 nb = rb[lane + dcu];
    float nd = nb.w;
    float d0 = fcx.x - nb.x, d1 = fcy.x - nb.y, d2 = fcz.x - nb.z;
    float d = (d0 * d0 + d1 * d1) + d2 * d2;
    d = d + (sprf + (float)((dcu - PR) * (dcu - PR)));
    int bt = (nd > dcen) & (d < bestd);
    bestd = bt ? d : bestd;
    bestp = bt ? (qbase + dcu - PR) : bestp;
  }
}

template<int DB, int DE>
__device__ inline void par_two_rows(const float4* __restrict__ bufA,
                                    const float4* __restrict__ bufB,
                                    int lane, f32x2 fcx, f32x2 fcy, f32x2 fcz,
                                    float dcen, int y, int x,
                                    int nyA, bool haveB,
                                    float& bestd, int& bestp) {
#pragma clang fp contract(off)
  int drA = nyA - y;
  par_pairs<DB, DE>(bufA, lane, fcx, fcy, fcz, dcen,
                    (float)(drA * drA), nyA * W + x, bestd, bestp);
  if (haveB) {
    int drB = nyA + 1 - y;
    par_pairs<DB, DE>(bufB, lane, fcx, fcy, fcz, dcen,
                      (float)(drB * drB), (nyA + 1) * W + x, bestd, bestp);
  }
}

__global__ __launch_bounds__(512, 4)
void k_par(const float4* __restrict__ pf, unsigned long long* __restrict__ pkeys) {
#pragma clang fp contract(off)
  __shared__ float4 aos[2][2][NSEG];       // [buf][row-of-pair][col]
  __shared__ unsigned long long m_k[8][64];
  int tid = threadIdx.x, lane = tid & 63, wave = tid >> 6;
  int b = blockIdx.x;                      // img*512 + y*4 + tile*2 + half
  int half = b & 1, tile = (b >> 1) & 1, y = (b >> 2) & 127, img = b >> 9;
  int x0 = tile * 64, x = x0 + lane;
  const float4* fimg = pf + img * PIMG;
  float4 fc = fimg[y * PSTR + x + KWIN];
  float dcen = fc.w;
  f32x2 fcx = { fc.x, fc.x }, fcy = { fc.y, fc.y }, fcz = { fc.z, fc.z };
  int ny0 = y - PR; if (ny0 < 0) ny0 = 0;
  int ny1 = y + PR; if (ny1 > H - 1) ny1 = H - 1;
  int nr = ny1 - ny0 + 1;                  // 21..41
  int h0 = nr >> 1;                        // rows in half 0
  int hb = half ? (ny0 + h0) : ny0;
  int he = half ? (ny1 + 1) : (ny0 + h0);
  int cnt = he - hb;                       // >= 10
  // pair staging: 2 rows x NSEG float4 = 2*208 float2; threads 0..207 stage
  // row A (float2 index sidx), threads 256..463 stage row B.
  int rsel = tid >> 8;                     // 0..1
  int sidx = tid & 255;                    // float2 index within row
  const int segoff = x0 + (KWIN - PR);     // staged cols = x0-PR .. x0+63+PR
  {
    int rA = hb;
    int rB = (hb + 1 < he) ? hb + 1 : hb;  // clamp (unused if no row B)
    int rr = rsel ? rB : rA;
    if (sidx < NSEG * 2) {
      float2 v = *(const float2*)(((const float*)(fimg + rr * PSTR + segoff)) + sidx * 2);
      *(float2*)(((float*)&aos[0][rsel][0]) + sidx * 2) = v;
    }
  }
  __syncthreads();
  float bestd = __builtin_inff();
  int bestp = y * W + x;
  int npairs = (cnt + 1) >> 1;
  for (int p = 0; p < npairs; ++p) {
    int kb = p & 1;
    float2 pv;
    bool pre = (p + 1 < npairs);
    if (pre) {                             // issue next-pair global loads early
      int nA = hb + 2 * (p + 1);
      int nB = (nA + 1 < he) ? nA + 1 : nA;
      int pr_row = rsel ? nB : nA;
      if (sidx < NSEG * 2)
        pv = *(const float2*)(((const float*)(fimg + pr_row * PSTR + segoff)) + sidx * 2);
    }
    int nyA = hb + 2 * p;
    bool haveB = (nyA + 1 < he);           // wave-uniform
    const float4* bufA = &aos[kb][0][0];
    const float4* bufB = &aos[kb][1][0];
    if      (wave == 0) par_two_rows< 0,  6>(bufA, bufB, lane, fcx, fcy, fcz, dcen, y, x, nyA, haveB, bestd, bestp);
    else if (wave == 1) par_two_rows< 6, 11>(bufA, bufB, lane, fcx, fcy, fcz, dcen, y, x, nyA, haveB, bestd, bestp);
    else if (wave == 2) par_two_rows<11, 16>(bufA, bufB, lane, fcx, fcy, fcz, dcen, y, x, nyA, haveB, bestd, bestp);
    else if (wave == 3) par_two_rows<16, 21>(bufA, bufB, lane, fcx, fcy, fcz, dcen, y, x, nyA, haveB, bestd, bestp);
    else if (wave == 4) par_two_rows<21, 26>(bufA, bufB, lane, fcx, fcy, fcz, dcen, y, x, nyA, haveB, bestd, bestp);
    else if (wave == 5) par_two_rows<26, 31>(bufA, bufB, lane, fcx, fcy, fcz, dcen, y, x, nyA, haveB, bestd, bestp);
    else if (wave == 6) par_two_rows<31, 36>(bufA, bufB, lane, fcx, fcy, fcz, dcen, y, x, nyA, haveB, bestd, bestp);
    else                par_two_rows<36, 41>(bufA, bufB, lane, fcx, fcy, fcz, dcen, y, x, nyA, haveB, bestd, bestp);
    if (pre && sidx < NSEG * 2)            // write other buffer: no race now
      *(float2*)(((float*)&aos[kb ^ 1][rsel][0]) + sidx * 2) = pv;
    __syncthreads();                       // publish next pair
  }
  // pack (d, q): inf (no candidate) sorts above all finite d
  m_k[wave][lane] =
      ((unsigned long long)__float_as_uint(bestd) << 32) | (unsigned)bestp;
  __syncthreads();
  if (wave == 0) {
    unsigned long long k = m_k[0][lane];
#pragma unroll
    for (int w = 1; w < 8; ++w) {
      unsigned long long kw = m_k[w][lane];
      k = (kw < k) ? kw : k;
    }
    pkeys[half * (IMGS * NP) + img * NP + y * W + x] = k;
  }
}

// ---------------- root chase, parent decoded on the fly from pkeys -------------
// R28: k_merge removed. parent(j) is a pure function of the two pkeys planes:
// k = min(k0,k1); parent = (d>400) ? j : q — decoded per step (same bits the
// old k_merge materialized). root[j] only ever transitions -1 -> final root
// (single aligned 4B write): racy read returns -1 (no shortcut, safe) or the
// correct root.
__global__ void k_root(const unsigned long long* __restrict__ pkeys,
                       int* __restrict__ root) {
  int i = blockIdx.x * blockDim.x + threadIdx.x;
  if (i >= IMGS * NP) return;
  int img = i / NP, p = i % NP;
  const unsigned long long* pk0 = pkeys + img * NP;
  const unsigned long long* pk1 = pkeys + IMGS * NP + img * NP;
  volatile int* rt = (volatile int*)(root + img * NP);
  auto dec = [&](int j) -> int {
    unsigned long long k0 = pk0[j], k1 = pk1[j];
    unsigned long long k = (k0 < k1) ? k0 : k1;
    float bd = __uint_as_float((unsigned)(k >> 32));
    return (bd > 400.0f) ? j : (int)(k & 0xffffffffu);  // sqrt(d) > max_dist
  };
  int r = dec(p);
#pragma unroll 1
  for (int it = 0; it < NP; ++it) {        // chains strictly increase density => acyclic
    int rr = rt[r];                        // published root of r (or -1)
    int pr = dec(r);
    if (rr >= 0) { r = rr; break; }
    if (pr == r) break;
    r = pr;
  }
  root[i] = r;
}

// ---------------- scan of root flags + final labels (fused, coalesced) ---------
// R28: root flags decoded from pkeys (parent==self <=> d>400 || q==self) —
// identical bits to the removed k_merge's parent array.
__global__ __launch_bounds__(1024)
void k_scanlabel(const unsigned long long* __restrict__ pkeys,
                 const int* __restrict__ root,
                 int* __restrict__ cums, int* __restrict__ out) {
  __shared__ int part[1024];
  int img = blockIdx.x;
  int t = threadIdx.x;                     // 1024 threads x 16 elements
  const unsigned long long* pk0 = pkeys + img * NP;
  const unsigned long long* pk1 = pkeys + IMGS * NP + img * NP;
  int base = t * 16;
  int f[16];
#pragma unroll
  for (int j = 0; j < 16; ++j) {
    int p = base + j;
    unsigned long long k0 = pk0[p], k1 = pk1[p];
    unsigned long long k = (k0 < k1) ? k0 : k1;
    float bd = __uint_as_float((unsigned)(k >> 32));
    int par = (bd > 400.0f) ? p : (int)(k & 0xffffffffu);
    f[j] = (par == p);
  }
  int s = 0;
#pragma unroll
  for (int j = 0; j < 16; ++j) s += f[j];
  part[t] = s;
  __syncthreads();
  for (int off = 1; off < 1024; off <<= 1) {
    int add = (t >= off) ? part[t - off] : 0;
    __syncthreads();
    part[t] += add;
    __syncthreads();
  }
  int run = part[t] - s;                   // exclusive prefix of this chunk
  int* c = cums + img * NP;
#pragma unroll
  for (int j = 0; j < 16; ++j) { run += f[j]; c[base + j] = run; }
  __threadfence_block();
  __syncthreads();                         // block-visible global writes
  const int* rimg = root + img * NP;
  int* oimg = out + img * NP;
  for (int j = t; j < NP; j += 1024) {
    int lab = c[rimg[j]] - 1;
    oimg[j] = (lab < MAXSEG - 1) ? lab : (MAXSEG - 1);
  }
}

extern "C" void kernel_launch(void* const* d_in, const int* in_sizes, int n_in,
                              void* d_out, int out_size, void* d_ws, size_t ws_size,
                              hipStream_t stream) {
  const float* x = (const float*)d_in[0];
  int* out = (int*)d_out;
  char* ws = (char*)d_ws;

  // workspace layout (~1.70 MB).
  // part (4 x IMGS*NP floats = 524288 B) aliases bufL — bufL dead after k_blur.
  // pkeys (2 x IMGS*NP u64 = 524288 B) aliases the same region — part dead
  // after k_densmerge; k_par writes pkeys after that (in-stream order).
  float4* pf   = (float4*)(ws);                         // 2*24576*16 = 786432
  float4* bufL = (float4*)(ws + 786432);                // 524288 (lab output)
  float* part  = (float*)(ws + 786432);                 // alias bufL, 524288
  unsigned long long* pkeys = (unsigned long long*)(ws + 786432);  // alias, 524288
  int* root    = (int*)(ws + 1441792);                  // 131072
  int* cums    = (int*)(ws + 1572864);                  // 131072

  const int total = IMGS * NP;                          // 32768
  const int ptotal = IMGS * PIMG;                       // 49152

  k_prep<<<(ptotal + 255) / 256, 256, 0, stream>>>(x, pf, bufL);
  k_blur<<<IMGS * H, 384, 0, stream>>>(bufL, pf);
  k_dens<<<1024, 512, 0, stream>>>(pf, part);
  k_densmerge<<<total / 256, 256, 0, stream>>>(part, pf, root);
  k_par<<<1024, 512, 0, stream>>>(pf, pkeys);
  k_root<<<total / 256, 256, 0, stream>>>(pkeys, root);
  k_scanlabel<<<IMGS, 1024, 0, stream>>>(pkeys, root, cums, out);
}

// Round 14
// 163.588 us; speedup vs baseline: 1.0658x; 1.0658x over previous
//
#include <hip/hip_runtime.h>
#include <math.h>

static constexpr int IMGS = 2;
static constexpr int H = 128, W = 128;
static constexpr int NP = H * W;           // 16384
static constexpr int KWIN = 30;            // quickshift window radius (ceil(3*10))
static constexpr int PR = 20;              // parent prune radius: dr^2+dc^2>400 can't win (MAX_DIST=20)
static constexpr int GR = 20;              // gaussian radius int(4*5+0.5)
static constexpr float INV = 0.005f;       // 0.5 / (10*10)
static constexpr int MAXSEG = 40;

// padded feature layout: row stride 192 float4, cols [30,158) hold the image.
// float4 = (L, a, b, dens); pads = (1e6,1e6,1e6,-inf).
static constexpr int PSTR = 192;
static constexpr int PIMG = H * PSTR;      // 24576 float4 per image
static constexpr int NSEG = 64 + 2 * PR;   // 104 staged float4 per k_par row

typedef float f32x2 __attribute__((ext_vector_type(2)));

// ---------------- prep: pf sentinel fill + rgb2lab into bufL -------------------
__global__ void k_prep(const float* __restrict__ x, float4* __restrict__ pf,
                       float4* __restrict__ bufL) {
#pragma clang fp contract(off)
  int i = blockIdx.x * blockDim.x + threadIdx.x;
  if (i < IMGS * PIMG) pf[i] = make_float4(1e6f, 1e6f, 1e6f, -__builtin_inff());
  if (i >= IMGS * NP) return;
  int img = i / NP, p = i % NP;
  const float* base = x + img * 3 * NP;
  float rgb[3] = { base[p], base[NP + p], base[2 * NP + p] };
  float lin[3];
  for (int c = 0; c < 3; ++c) {
    float v = rgb[c];
    lin[c] = (v > 0.04045f) ? powf((v + 0.055f) / 1.055f, 2.4f) : (v / 12.92f);
  }
  const float M[3][3] = {{0.412453f, 0.357580f, 0.180423f},
                         {0.212671f, 0.715160f, 0.072169f},
                         {0.019334f, 0.119193f, 0.950227f}};
  const float wp[3] = {0.95047f, 1.0f, 1.08883f};
  float f[3];
  for (int j = 0; j < 3; ++j) {
    float s = lin[0] * M[j][0];
    s = s + lin[1] * M[j][1];
    s = s + lin[2] * M[j][2];
    float xyz = s / wp[j];
    f[j] = (xyz > 0.008856f) ? cbrtf(fmaxf(xyz, 1e-8f))
                             : (7.787f * xyz + (float)(16.0 / 116.0));
  }
  float L = 116.0f * f[1] - 16.0f;
  float a = 500.0f * (f[0] - f[1]);
  float b = 200.0f * (f[1] - f[2]);
  bufL[i] = make_float4(L, a, b, 0.0f);
}

// ---------------- fused separable gaussian (V then H), symmetric pad -----------
__global__ __launch_bounds__(384)
void k_blur(const float4* __restrict__ bufL, float4* __restrict__ pf) {
#pragma clang fp contract(off)
  __shared__ float w[2 * GR + 1];
  __shared__ float mid[3][128];
  if (threadIdx.x == 0) {
    double k[2 * GR + 1];
    double s = 0.0;
    for (int i = -GR; i <= GR; ++i) {
      double t = (double)i / 5.0;
      double v = exp(-0.5 * t * t);
      k[i + GR] = v;
      s += v;
    }
    for (int i = 0; i < 2 * GR + 1; ++i) w[i] = (float)(k[i] / s);
  }
  __syncthreads();
  int tid = threadIdx.x;
  int c = tid >> 7;                         // 0..2
  int xx = tid & 127;
  int b = blockIdx.x;                       // img*128 + y
  int y = b & 127, img = b >> 7;
  const float* base = (const float*)(bufL + img * NP);
  float a = 0.0f;
  for (int t = 0; t <= 2 * GR; ++t) {
    int yy = y - GR + t;
    if (yy < 0) yy = -yy - 1;
    if (yy >= H) yy = 2 * H - 1 - yy;
    a = a + w[t] * base[(yy * W + xx) * 4 + c];
  }
  mid[c][xx] = a;
  __syncthreads();
  float o = 0.0f;
  for (int t = 0; t <= 2 * GR; ++t) {
    int xq = xx - GR + t;
    if (xq < 0) xq = -xq - 1;
    if (xq >= W) xq = 2 * W - 1 - xq;
    o = o + w[t] * mid[c][xq];
  }
  ((float*)(pf + img * PIMG + y * PSTR + xx + KWIN))[c] = o;  // 4B store, no race
}

// ---------------- density: 2-center rows x 4-way row-split, barrier-free -------
// (validated best: 50.4us @ R11. 4-center (R12) spills — do not revisit.
// Density keeps the FULL 61x61 window: no distance cutoff, far terms ~exp(-2).)
__device__ inline void dens_row2(const float4* __restrict__ grow,
                                 float4 fc0, float4 fc1,
                                 float sprf0, float sprf1, int lane,
                                 float& acc0, float& acc1) {
#pragma clang fp contract(off)
  const f32x2 nInv = { -INV, -INV };
#pragma unroll
  for (int d0 = 0; d0 + 1 < 61; d0 += 2) {
    float4 nb0 = grow[lane + d0];
    float4 nb1 = grow[lane + d0 + 1];
    float c0 = (float)((d0 - KWIN) * (d0 - KWIN));
    float c1 = (float)((d0 + 1 - KWIN) * (d0 + 1 - KWIN));
    // center 0
    f32x2 dx0 = { fc0.x - nb0.x, fc0.x - nb1.x };
    f32x2 dy0 = { fc0.y - nb0.y, fc0.y - nb1.y };
    f32x2 dz0 = { fc0.z - nb0.z, fc0.z - nb1.z };
    f32x2 dd0 = (dx0 * dx0 + dy0 * dy0) + dz0 * dz0;
    f32x2 sp0 = { sprf0 + c0, sprf0 + c1 };   // exact: ints < 2^11 (or inf)
    dd0 = dd0 + sp0;
    f32x2 e0 = dd0 * nInv;                    // bit == -(d*INV)
    acc0 = acc0 + __expf(e0.x);               // in-order within row
    acc0 = acc0 + __expf(e0.y);
    // center 1 (same loaded neighbors)
    f32x2 dx1 = { fc1.x - nb0.x, fc1.x - nb1.x };
    f32x2 dy1 = { fc1.y - nb0.y, fc1.y - nb1.y };
    f32x2 dz1 = { fc1.z - nb0.z, fc1.z - nb1.z };
    f32x2 dd1 = (dx1 * dx1 + dy1 * dy1) + dz1 * dz1;
    f32x2 sp1 = { sprf1 + c0, sprf1 + c1 };
    dd1 = dd1 + sp1;
    f32x2 e1 = dd1 * nInv;
    acc1 = acc1 + __expf(e1.x);
    acc1 = acc1 + __expf(e1.y);
  }
  {                                           // dc = 60 tail, both centers
    float4 nb = grow[lane + 60];
    float ct = (float)((60 - KWIN) * (60 - KWIN));
    float a0 = fc0.x - nb.x, a1 = fc0.y - nb.y, a2 = fc0.z - nb.z;
    float d0 = (a0 * a0 + a1 * a1) + a2 * a2;
    d0 = d0 + (sprf0 + ct);
    acc0 = acc0 + __expf(-d0 * INV);
    float b0 = fc1.x - nb.x, b1 = fc1.y - nb.y, b2 = fc1.z - nb.z;
    float d1 = (b0 * b0 + b1 * b1) + b2 * b2;
    d1 = d1 + (sprf1 + ct);
    acc1 = acc1 + __expf(-d1 * INV);
  }
}

__global__ __launch_bounds__(512, 4)
void k_dens(const float4* __restrict__ pf, float* __restrict__ part) {
#pragma clang fp contract(off)
  __shared__ float pbuf[8][2][64];
  int tid = threadIdx.x;
  int lane = tid & 63;
  int wave = tid >> 6;
  int b = blockIdx.x;                      // 1024: img*512 + ygrp*8 + tile*4 + q
  int q = b & 3, tile = (b >> 2) & 1, ygrp = (b >> 3) & 63, img = b >> 9;
  int y0 = ygrp * 2, y1 = y0 + 1;
  int x0 = tile * 64;
  const float4* fimg = pf + img * PIMG;
  float4 fc0 = fimg[y0 * PSTR + x0 + lane + KWIN];
  float4 fc1 = fimg[y1 * PSTR + x0 + lane + KWIN];
  int lo = y0 - KWIN; if (lo < 0) lo = 0;
  int hi = y1 + KWIN; if (hi > H - 1) hi = H - 1;
  int nr = hi - lo + 1;                    // 32..62 union rows
  int c = q * 8 + wave;                    // 0..31 ascending row chunks
  int base = nr >> 5, rem = nr & 31;       // base>=1, so all chunks nonempty
  int cnt = base + (c < rem ? 1 : 0);
  int start = lo + c * base + (c < rem ? c : rem);
  float acc0 = 0.0f, acc1 = 0.0f;
  for (int r = 0; r < cnt; ++r) {
    int ny = start + r;
    int dr0 = ny - y0, dr1 = ny - y1;
    // wave-uniform activity guards; inactive => sprf=inf => exact +0.0 terms
    float s0 = (ny <= y0 + KWIN) ? (float)(dr0 * dr0) : __builtin_inff();
    float s1 = (ny >= y1 - KWIN) ? (float)(dr1 * dr1) : __builtin_inff();
    const float4* grow = fimg + ny * PSTR + x0;
    dens_row2(grow, fc0, fc1, s0, s1, lane, acc0, acc1);
  }
  pbuf[wave][0][lane] = acc0;              // publish row-chunk partials
  pbuf[wave][1][lane] = acc1;
  __syncthreads();
  if (wave < 2) {                          // wave w folds center row y0+w
    float a = pbuf[0][wave][lane];
#pragma unroll
    for (int w = 1; w < 8; ++w) a = a + pbuf[w][wave][lane];
    part[q * (IMGS * NP) + img * NP + (y0 + wave) * W + x0 + lane] = a;
  }
}

// ---------------- fold the 4 row-quarter partials into pf.w --------------------
// Ascending-q = ascending-row order, left-to-right: bitwise-deterministic.
__global__ void k_densmerge(const float* __restrict__ part, float4* __restrict__ pf) {
#pragma clang fp contract(off)
  int i = blockIdx.x * blockDim.x + threadIdx.x;
  if (i >= IMGS * NP) return;
  int img = i / NP, p = i % NP, y = p >> 7, x = p & 127;
  float s = ((part[i] + part[IMGS * NP + i]) + part[2 * IMGS * NP + i])
            + part[3 * IMGS * NP + i];
  pf[img * PIMG + y * PSTR + x + KWIN].w = s;
}

// ---------------- parent: +-20 pruned window, half-split, AoS b128, pairs ------
// (R11, validated: semantic prune — MAX_DIST=20 means dr^2+dc^2>400 candidates
// can never be sub-threshold winners; 41x41 window = 45% of the work.
// R13's pkeys-decode tail fusion REGRESSED (serial chase re-derives parent);
// materializing parent once in k_merge is the validated structure.)
template<int DB, int DE>
__device__ inline void par_pairs(const float4* __restrict__ rb,
                                 int lane, f32x2 fcx, f32x2 fcy, f32x2 fcz,
                                 float dcen, float sprf, int qbase,
                                 float& bestd, int& bestp) {
#pragma clang fp contract(off)
#pragma unroll
  for (int d0 = DB; d0 + 1 < DE; d0 += 2) {
    int i0 = lane + d0;
    float4 nb0 = rb[i0];
    float4 nb1 = rb[i0 + 1];
    f32x2 nx = { nb0.x, nb1.x };
    f32x2 nv = { nb0.y, nb1.y };
    f32x2 nz = { nb0.z, nb1.z };
    f32x2 nw = { nb0.w, nb1.w };
    f32x2 dx = fcx - nx, dy = fcy - nv, dz = fcz - nz;
    f32x2 dd = (dx * dx + dy * dy) + dz * dz;
    f32x2 sp = { sprf + (float)((d0 - PR) * (d0 - PR)),
                 sprf + (float)((d0 + 1 - PR) * (d0 + 1 - PR)) };
    dd = dd + sp;                          // exact (ints < 2^11)
    int b0 = (nw.x > dcen) & (dd.x < bestd);
    bestd = b0 ? dd.x : bestd;
    bestp = b0 ? (qbase + d0 - PR) : bestp;
    int b1 = (nw.y > dcen) & (dd.y < bestd);
    bestd = b1 ? dd.y : bestd;
    bestp = b1 ? (qbase + d0 + 1 - PR) : bestp;
  }
  if constexpr ((DE - DB) & 1) {           // scalar tail
    constexpr int dcu = DE - 1;
    float4 nb = rb[lane + dcu];
    float nd = nb.w;
    float d0 = fcx.x - nb.x, d1 = fcy.x - nb.y, d2 = fcz.x - nb.z;
    float d = (d0 * d0 + d1 * d1) + d2 * d2;
    d = d + (sprf + (float)((dcu - PR) * (dcu - PR)));
    int bt = (nd > dcen) & (d < bestd);
    bestd = bt ? d : bestd;
    bestp = bt ? (qbase + dcu - PR) : bestp;
  }
}

template<int DB, int DE>
__device__ inline void par_two_rows(const float4* __restrict__ bufA,
                                    const float4* __restrict__ bufB,
                                    int lane, f32x2 fcx, f32x2 fcy, f32x2 fcz,
                                    float dcen, int y, int x,
                                    int nyA, bool haveB,
                                    float& bestd, int& bestp) {
#pragma clang fp contract(off)
  int drA = nyA - y;
  par_pairs<DB, DE>(bufA, lane, fcx, fcy, fcz, dcen,
                    (float)(drA * drA), nyA * W + x, bestd, bestp);
  if (haveB) {
    int drB = nyA + 1 - y;
    par_pairs<DB, DE>(bufB, lane, fcx, fcy, fcz, dcen,
                      (float)(drB * drB), (nyA + 1) * W + x, bestd, bestp);
  }
}

__global__ __launch_bounds__(512, 4)
void k_par(const float4* __restrict__ pf, unsigned long long* __restrict__ pkeys) {
#pragma clang fp contract(off)
  __shared__ float4 aos[2][2][NSEG];       // [buf][row-of-pair][col]
  __shared__ unsigned long long m_k[8][64];
  int tid = threadIdx.x, lane = tid & 63, wave = tid >> 6;
  int b = blockIdx.x;                      // img*512 + y*4 + tile*2 + half
  int half = b & 1, tile = (b >> 1) & 1, y = (b >> 2) & 127, img = b >> 9;
  int x0 = tile * 64, x = x0 + lane;
  const float4* fimg = pf + img * PIMG;
  float4 fc = fimg[y * PSTR + x + KWIN];
  float dcen = fc.w;
  f32x2 fcx = { fc.x, fc.x }, fcy = { fc.y, fc.y }, fcz = { fc.z, fc.z };
  int ny0 = y - PR; if (ny0 < 0) ny0 = 0;
  int ny1 = y + PR; if (ny1 > H - 1) ny1 = H - 1;
  int nr = ny1 - ny0 + 1;                  // 21..41
  int h0 = nr >> 1;                        // rows in half 0
  int hb = half ? (ny0 + h0) : ny0;
  int he = half ? (ny1 + 1) : (ny0 + h0);
  int cnt = he - hb;                       // >= 10
  // pair staging: 2 rows x NSEG float4 = 2*208 float2; threads 0..207 stage
  // row A (float2 index sidx), threads 256..463 stage row B.
  int rsel = tid >> 8;                     // 0..1
  int sidx = tid & 255;                    // float2 index within row
  const int segoff = x0 + (KWIN - PR);     // staged cols = x0-PR .. x0+63+PR
  {
    int rA = hb;
    int rB = (hb + 1 < he) ? hb + 1 : hb;  // clamp (unused if no row B)
    int rr = rsel ? rB : rA;
    if (sidx < NSEG * 2) {
      float2 v = *(const float2*)(((const float*)(fimg + rr * PSTR + segoff)) + sidx * 2);
      *(float2*)(((float*)&aos[0][rsel][0]) + sidx * 2) = v;
    }
  }
  __syncthreads();
  float bestd = __builtin_inff();
  int bestp = y * W + x;
  int npairs = (cnt + 1) >> 1;
  for (int p = 0; p < npairs; ++p) {
    int kb = p & 1;
    float2 pv;
    bool pre = (p + 1 < npairs);
    if (pre) {                             // issue next-pair global loads early
      int nA = hb + 2 * (p + 1);
      int nB = (nA + 1 < he) ? nA + 1 : nA;
      int pr_row = rsel ? nB : nA;
      if (sidx < NSEG * 2)
        pv = *(const float2*)(((const float*)(fimg + pr_row * PSTR + segoff)) + sidx * 2);
    }
    int nyA = hb + 2 * p;
    bool haveB = (nyA + 1 < he);           // wave-uniform
    const float4* bufA = &aos[kb][0][0];
    const float4* bufB = &aos[kb][1][0];
    if      (wave == 0) par_two_rows< 0,  6>(bufA, bufB, lane, fcx, fcy, fcz, dcen, y, x, nyA, haveB, bestd, bestp);
    else if (wave == 1) par_two_rows< 6, 11>(bufA, bufB, lane, fcx, fcy, fcz, dcen, y, x, nyA, haveB, bestd, bestp);
    else if (wave == 2) par_two_rows<11, 16>(bufA, bufB, lane, fcx, fcy, fcz, dcen, y, x, nyA, haveB, bestd, bestp);
    else if (wave == 3) par_two_rows<16, 21>(bufA, bufB, lane, fcx, fcy, fcz, dcen, y, x, nyA, haveB, bestd, bestp);
    else if (wave == 4) par_two_rows<21, 26>(bufA, bufB, lane, fcx, fcy, fcz, dcen, y, x, nyA, haveB, bestd, bestp);
    else if (wave == 5) par_two_rows<26, 31>(bufA, bufB, lane, fcx, fcy, fcz, dcen, y, x, nyA, haveB, bestd, bestp);
    else if (wave == 6) par_two_rows<31, 36>(bufA, bufB, lane, fcx, fcy, fcz, dcen, y, x, nyA, haveB, bestd, bestp);
    else                par_two_rows<36, 41>(bufA, bufB, lane, fcx, fcy, fcz, dcen, y, x, nyA, haveB, bestd, bestp);
    if (pre && sidx < NSEG * 2)            // write other buffer: no race now
      *(float2*)(((float*)&aos[kb ^ 1][rsel][0]) + sidx * 2) = pv;
    __syncthreads();                       // publish next pair
  }
  // pack (d, q): inf (no candidate) sorts above all finite d
  m_k[wave][lane] =
      ((unsigned long long)__float_as_uint(bestd) << 32) | (unsigned)bestp;
  __syncthreads();
  if (wave == 0) {
    unsigned long long k = m_k[0][lane];
#pragma unroll
    for (int w = 1; w < 8; ++w) {
      unsigned long long kw = m_k[w][lane];
      k = (kw < k) ? kw : k;
    }
    pkeys[half * (IMGS * NP) + img * NP + y * W + x] = k;
  }
}

// ---------------- merge halves -> parent, init root=-1 -------------------------
__global__ void k_merge(const unsigned long long* __restrict__ pkeys,
                        int* __restrict__ parent, int* __restrict__ root) {
  int i = blockIdx.x * blockDim.x + threadIdx.x;
  if (i >= IMGS * NP) return;
  unsigned long long k0 = pkeys[i], k1 = pkeys[IMGS * NP + i];
  unsigned long long k = (k0 < k1) ? k0 : k1;
  float bd = __uint_as_float((unsigned)(k >> 32));
  int p = i % NP;
  parent[i] = (bd > 400.0f) ? p : (int)(k & 0xffffffffu);  // sqrt(d) > max_dist
  root[i] = -1;                            // enables the k_root shortcut
}

// ---------------- root chase with published-root shortcut ----------------------
// root[j] only ever transitions -1 -> final root of j (single aligned 4B
// write), so a racy read returns -1 (no shortcut — safe) or the correct root.
__global__ void k_root(const int* __restrict__ parent, int* __restrict__ root) {
  int i = blockIdx.x * blockDim.x + threadIdx.x;
  if (i >= IMGS * NP) return;
  int img = i / NP, p = i % NP;
  const int* par = parent + img * NP;
  volatile int* rt = (volatile int*)(root + img * NP);
  int r = par[p];
#pragma unroll 1
  for (int it = 0; it < NP; ++it) {        // chains strictly increase density => acyclic
    int rr = rt[r];                        // published root of r (or -1)
    int pr = par[r];
    if (rr >= 0) { r = rr; break; }
    if (pr == r) break;
    r = pr;
  }
  root[i] = r;
}

// ---------------- scan of root flags + final labels (fused, coalesced) ---------
__global__ __launch_bounds__(1024)
void k_scanlabel(const int* __restrict__ parent, const int* __restrict__ root,
                 int* __restrict__ cums, int* __restrict__ out) {
  __shared__ int part[1024];
  int img = blockIdx.x;
  int t = threadIdx.x;                     // 1024 threads x 16 elements
  const int* par = parent + img * NP;
  int base = t * 16;
  int f[16];
  const int4* p4 = (const int4*)(par + base);
#pragma unroll
  for (int j = 0; j < 4; ++j) {
    int4 v = p4[j];
    f[4 * j + 0] = (v.x == base + 4 * j + 0);
    f[4 * j + 1] = (v.y == base + 4 * j + 1);
    f[4 * j + 2] = (v.z == base + 4 * j + 2);
    f[4 * j + 3] = (v.w == base + 4 * j + 3);
  }
  int s = 0;
#pragma unroll
  for (int j = 0; j < 16; ++j) s += f[j];
  part[t] = s;
  __syncthreads();
  for (int off = 1; off < 1024; off <<= 1) {
    int add = (t >= off) ? part[t - off] : 0;
    __syncthreads();
    part[t] += add;
    __syncthreads();
  }
  int run = part[t] - s;                   // exclusive prefix of this chunk
  int* c = cums + img * NP;
#pragma unroll
  for (int j = 0; j < 16; ++j) { run += f[j]; c[base + j] = run; }
  __threadfence_block();
  __syncthreads();                         // block-visible global writes
  const int* rimg = root + img * NP;
  int* oimg = out + img * NP;
  for (int j = t; j < NP; j += 1024) {
    int lab = c[rimg[j]] - 1;
    oimg[j] = (lab < MAXSEG - 1) ? lab : (MAXSEG - 1);
  }
}

extern "C" void kernel_launch(void* const* d_in, const int* in_sizes, int n_in,
                              void* d_out, int out_size, void* d_ws, size_t ws_size,
                              hipStream_t stream) {
  const float* x = (const float*)d_in[0];
  int* out = (int*)d_out;
  char* ws = (char*)d_ws;

  // workspace layout (~1.70 MB).
  // part (4 x IMGS*NP floats = 524288 B) aliases bufL — bufL dead after k_blur.
  // pkeys (2 x IMGS*NP u64 = 524288 B) aliases the same region — part dead
  // after k_densmerge; k_par writes pkeys after that (in-stream order).
  float4* pf   = (float4*)(ws);                         // 2*24576*16 = 786432
  float4* bufL = (float4*)(ws + 786432);                // 524288 (lab output)
  float* part  = (float*)(ws + 786432);                 // alias bufL, 524288
  unsigned long long* pkeys = (unsigned long long*)(ws + 786432);  // alias, 524288
  int* parent  = (int*)(ws + 1310720);                  // 131072
  int* root    = (int*)(ws + 1441792);                  // 131072
  int* cums    = (int*)(ws + 1572864);                  // 131072

  const int total = IMGS * NP;                          // 32768
  const int ptotal = IMGS * PIMG;                       // 49152

  k_prep<<<(ptotal + 255) / 256, 256, 0, stream>>>(x, pf, bufL);
  k_blur<<<IMGS * H, 384, 0, stream>>>(bufL, pf);
  k_dens<<<1024, 512, 0, stream>>>(pf, part);
  k_densmerge<<<total / 256, 256, 0, stream>>>(part, pf);
  k_par<<<1024, 512, 0, stream>>>(pf, pkeys);
  k_merge<<<total / 256, 256, 0, stream>>>(pkeys, parent, root);
  k_root<<<total / 256, 256, 0, stream>>>(parent, root);
  k_scanlabel<<<IMGS, 1024, 0, stream>>>(parent, root, cums, out);
}